// Round 2
// baseline (10911.726 us; speedup 1.0000x reference)
//
#include <hip/hip_runtime.h>
#include <stdint.h>

// ---------------- constants ----------------
#define NB   2048          // batch
#define SEQ  17
#define DIM  512
#define NTOK (NB * SEQ)    // 34816 rows (= 272*128)
#define NPAT (NB * 16)     // 32768 rows (= 256*128)
#define HALFTOK (NTOK / 2) // 17408 (= 136*128), batch boundary at b=1024

typedef __bf16 v8bf __attribute__((ext_vector_type(8)));
typedef float  f32x4 __attribute__((ext_vector_type(4)));

typedef const __attribute__((address_space(1))) void GVoid;
typedef __attribute__((address_space(3))) void LVoid;

__device__ __forceinline__ uint16_t f2bf(float f) {
  uint32_t u = __float_as_uint(f);
  uint32_t r = u + 0x7FFFu + ((u >> 16) & 1u);
  return (uint16_t)(r >> 16);
}
__device__ __forceinline__ float bf2f(uint16_t h) {
  return __uint_as_float(((uint32_t)h) << 16);
}
__device__ __forceinline__ void load16_lds(const void* g, void* l) {
  __builtin_amdgcn_global_load_lds((GVoid*)g, (LVoid*)l, 16, 0, 0);
}

// ---------------- weight transpose+cast: (K,N) f32 -> (N,K) bf16 ----------------
__global__ __launch_bounds__(256) void transpose_cast(
    const float* __restrict__ in, uint16_t* __restrict__ out, int K, int N) {
  __shared__ uint16_t t[64][65];
  int k0 = blockIdx.y * 64, n0 = blockIdx.x * 64;
  int tid = threadIdx.x;
  int c = tid & 63, r0 = tid >> 6;
#pragma unroll
  for (int i = 0; i < 16; i++) {
    int r = i * 4 + r0;
    t[c][r] = f2bf(in[(size_t)(k0 + r) * N + n0 + c]);
  }
  __syncthreads();
#pragma unroll
  for (int i = 0; i < 16; i++) {
    int rn = i * 4 + r0;
    out[(size_t)(n0 + rn) * K + k0 + c] = t[rn][c];
  }
}

// ---------------- conv (16x16 kernel, pad 7/8) + patchify -> p bf16 (NB*16, 192) ----------------
__global__ __launch_bounds__(256) void conv_patch(
    const float* __restrict__ x, const float* __restrict__ w,
    const float* __restrict__ cb, uint16_t* __restrict__ p) {
  __shared__ float ws[2304];                       // (3,3,16,16)
  int tid = threadIdx.x;
  for (int i = tid; i < 2304; i += 256) ws[i] = w[i];
  __syncthreads();
  int gid = blockIdx.x * 256 + tid;                // NB*3072 outputs
  int b = gid / 3072;
  int r = gid % 3072;
  int o = r / 1024;
  int yy = (r % 1024) / 32;
  int xx = r % 32;
  const float* xb = x + (size_t)b * 3072;
  float acc = cb[o];
  for (int i = 0; i < 3; i++) {
    const float* xc = xb + i * 1024;
    const float* wc = ws + o * 768 + i * 256;
    for (int ky = 0; ky < 16; ky++) {
      int yin = yy - 7 + ky;
      if (yin < 0 || yin > 31) continue;
      int kx0 = max(0, 7 - xx), kx1 = min(15, 38 - xx);
      const float* xrow = xc + yin * 32 + xx - 7;
      const float* wrow = wc + ky * 16;
      for (int kx = kx0; kx <= kx1; kx++) acc += xrow[kx] * wrow[kx];
    }
  }
  int patch = (yy >> 3) * 4 + (xx >> 3);
  int feat = o * 64 + (yy & 7) * 8 + (xx & 7);
  p[((size_t)b * 16 + patch) * 192 + feat] = f2bf(acc);
}

// ---------------- GEMM: C(MxN) = A(M x K, lda) * W^T(N x K, ldw) + bias ----------
// EPI: 0=bias->bf16  1=bias+leaky->bf16  2=bias+gelu->bf16  3=in-place f32 accumulate (outf += v)
//      4=patch scatter + pos_emb -> f32
template <int EPI>
__global__ __launch_bounds__(256) void gemm_bf16(
    const uint16_t* __restrict__ A, const uint16_t* __restrict__ W,
    const float* __restrict__ bias, uint16_t* __restrict__ outb,
    float* __restrict__ outf, const float* __restrict__ pos,
    int M, int N, int K, int lda, int ldw, int ldo) {
  __shared__ uint16_t As[128 * 64];
  __shared__ uint16_t Bs[128 * 64];
  const int tid = threadIdx.x;
  const int w = tid >> 6, l = tid & 63;
  const int lr = l & 15, lk = l >> 4;
  const int wr = w >> 1, wc = w & 1;
  const int m0 = blockIdx.y * 128, n0 = blockIdx.x * 128;

  f32x4 acc[4][4];
#pragma unroll
  for (int i = 0; i < 4; i++)
#pragma unroll
    for (int j = 0; j < 4; j++) acc[i][j] = (f32x4){0.f, 0.f, 0.f, 0.f};

  const int gr = l >> 3;        // row within 8-row segment
  const int gc = (l & 7) * 8;   // element col
  const int nkt = K >> 6;
  for (int kt = 0; kt < nkt; kt++) {
    const uint16_t* Ab = A + (size_t)m0 * lda + kt * 64;
    const uint16_t* Bb = W + (size_t)n0 * ldw + kt * 64;
#pragma unroll
    for (int i = 0; i < 4; i++) {
      int seg = w * 4 + i;
      int r = seg * 8 + gr;
      load16_lds(Ab + (size_t)r * lda + gc, &As[seg * 512]);
      load16_lds(Bb + (size_t)r * ldw + gc, &Bs[seg * 512]);
    }
    __syncthreads();
#pragma unroll
    for (int kk = 0; kk < 64; kk += 32) {
      v8bf a[4], b[4];
#pragma unroll
      for (int mi = 0; mi < 4; mi++)
        a[mi] = *(const v8bf*)&As[(wr * 64 + mi * 16 + lr) * 64 + kk + lk * 8];
#pragma unroll
      for (int ni = 0; ni < 4; ni++)
        b[ni] = *(const v8bf*)&Bs[(wc * 64 + ni * 16 + lr) * 64 + kk + lk * 8];
#pragma unroll
      for (int mi = 0; mi < 4; mi++)
#pragma unroll
        for (int ni = 0; ni < 4; ni++)
          acc[mi][ni] = __builtin_amdgcn_mfma_f32_16x16x32_bf16(a[mi], b[ni], acc[mi][ni], 0, 0, 0);
    }
    __syncthreads();
  }

#pragma unroll
  for (int mi = 0; mi < 4; mi++) {
#pragma unroll
    for (int ni = 0; ni < 4; ni++) {
      int col = n0 + wc * 64 + ni * 16 + lr;
      float bv = bias ? bias[col] : 0.f;
#pragma unroll
      for (int q = 0; q < 4; q++) {
        int row = m0 + wr * 64 + mi * 16 + lk * 4 + q;
        float v = acc[mi][ni][q] + bv;
        if (EPI == 0) {
          outb[(size_t)row * ldo + col] = f2bf(v);
        } else if (EPI == 1) {
          v = v > 0.f ? v : 0.1f * v;
          outb[(size_t)row * ldo + col] = f2bf(v);
        } else if (EPI == 2) {
          v = 0.5f * v * (1.f + erff(v * 0.70710678118654752f));
          outb[(size_t)row * ldo + col] = f2bf(v);
        } else if (EPI == 3) {
          outf[(size_t)row * ldo + col] += v;
        } else {
          int bb = row >> 4, ss = row & 15;
          outf[((size_t)bb * 17 + ss) * 512 + col] = v + pos[ss * 512 + col];
        }
      }
    }
  }
}

// ---------------- LayerNorm rows of h (f32) -> bf16 ----------------
__global__ __launch_bounds__(256) void ln_kernel(
    const float* __restrict__ h, const float* __restrict__ s,
    const float* __restrict__ b, uint16_t* __restrict__ out) {
  int row = blockIdx.x;
  const float* x = h + (size_t)row * 512;
  int tid = threadIdx.x;
  float v0 = x[tid], v1 = x[tid + 256];
  float sum = v0 + v1, sq = v0 * v0 + v1 * v1;
#pragma unroll
  for (int off = 1; off < 64; off <<= 1) {
    sum += __shfl_xor(sum, off);
    sq += __shfl_xor(sq, off);
  }
  __shared__ float sm[4], sv[4];
  int wid = tid >> 6;
  if ((tid & 63) == 0) { sm[wid] = sum; sv[wid] = sq; }
  __syncthreads();
  sum = sm[0] + sm[1] + sm[2] + sm[3];
  sq = sv[0] + sv[1] + sv[2] + sv[3];
  float mean = sum * (1.f / 512.f);
  float var = sq * (1.f / 512.f) - mean * mean;
  float rs = rsqrtf(var + 1e-5f);
  out[(size_t)row * 512 + tid] = f2bf((v0 - mean) * rs * s[tid] + b[tid]);
  out[(size_t)row * 512 + tid + 256] = f2bf((v1 - mean) * rs * s[tid + 256] + b[tid + 256]);
}

// ---------------- attention per (b,h): 64 threads; qkv points at a half-batch buffer ----------
__global__ __launch_bounds__(64) void attn_kernel(
    const uint16_t* __restrict__ qkv, uint16_t* __restrict__ o, int tok0) {
  int bh = blockIdx.x;
  int b = bh >> 4, h = bh & 15;              // b local to this half
  __shared__ float Q[17][32], Kk[17][32], V[17][32], P[17][18];
  int tid = threadIdx.x;
  const uint16_t* base = qkv + (size_t)b * SEQ * 1536 + h * 32;
  for (int idx = tid; idx < 544; idx += 64) {
    int s = idx >> 5, d = idx & 31;
    const uint16_t* rp = base + (size_t)s * 1536 + d;
    Q[s][d] = bf2f(rp[0]);
    Kk[s][d] = bf2f(rp[512]);
    V[s][d] = bf2f(rp[1024]);
  }
  __syncthreads();
  for (int idx = tid; idx < 289; idx += 64) {
    int i = idx / 17, j = idx % 17;
    float acc = 0.f;
#pragma unroll
    for (int d = 0; d < 32; d++) acc += Q[i][d] * Kk[j][d];
    P[i][j] = acc * 0.17677669529663687f;   // 1/sqrt(32)
  }
  __syncthreads();
  if (tid < 17) {
    float m = -1e30f;
    for (int j = 0; j < 17; j++) m = fmaxf(m, P[tid][j]);
    float sum = 0.f;
    for (int j = 0; j < 17; j++) { float e = __expf(P[tid][j] - m); P[tid][j] = e; sum += e; }
    float inv = 1.f / sum;
    for (int j = 0; j < 17; j++) P[tid][j] *= inv;
  }
  __syncthreads();
  uint16_t* ob = o + ((size_t)tok0 + (size_t)b * SEQ) * 512 + h * 32;
  for (int idx = tid; idx < 544; idx += 64) {
    int s = idx >> 5, d = idx & 31;
    float acc = 0.f;
#pragma unroll
    for (int t = 0; t < 17; t++) acc += P[s][t] * V[t][d];
    ob[(size_t)s * 512 + d] = f2bf(acc);
  }
}

// ---------------- cls token row fill ----------------
__global__ void fill_cls(const float* __restrict__ cls_tok,
                         const float* __restrict__ pos, float* __restrict__ h) {
  int b = blockIdx.x, d = threadIdx.x;
  h[((size_t)b * SEQ + 16) * 512 + d] = cls_tok[d] + pos[16 * 512 + d];
}

// ---------------- final LN (row 0) + classifier ----------------
__global__ __launch_bounds__(64) void final_head(
    const float* __restrict__ h, const float* __restrict__ fs,
    const float* __restrict__ fb, const float* __restrict__ cw,
    const float* __restrict__ cb, float* __restrict__ out) {
  int b = blockIdx.x;
  const float* x = h + (size_t)b * SEQ * 512;   // row s=0
  int l = threadIdx.x;
  float v[8];
  float sum = 0.f, sq = 0.f;
#pragma unroll
  for (int i = 0; i < 8; i++) { v[i] = x[l * 8 + i]; sum += v[i]; sq += v[i] * v[i]; }
#pragma unroll
  for (int off = 1; off < 64; off <<= 1) { sum += __shfl_xor(sum, off); sq += __shfl_xor(sq, off); }
  float mean = sum * (1.f / 512.f);
  float var = sq * (1.f / 512.f) - mean * mean;
  float rs = rsqrtf(var + 1e-5f);
  __shared__ float n[512];
#pragma unroll
  for (int i = 0; i < 8; i++) n[l * 8 + i] = (v[i] - mean) * rs * fs[l * 8 + i] + fb[l * 8 + i];
  __syncthreads();
  if (l < 10) {
    float acc = cb[l];
    for (int d = 0; d < 512; d++) acc += n[d] * cw[d * 10 + l];
    out[(size_t)b * 10 + l] = acc;
  }
}

// ---------------- launch ----------------
extern "C" void kernel_launch(void* const* d_in, const int* in_sizes, int n_in,
                              void* d_out, int out_size, void* d_ws, size_t ws_size,
                              hipStream_t stream) {
  const float* x       = (const float*)d_in[0];
  const float* conv_w  = (const float*)d_in[1];
  const float* conv_b  = (const float*)d_in[2];
  const float* h_w1    = (const float*)d_in[3];
  const float* h_b1    = (const float*)d_in[4];
  const float* h_w2    = (const float*)d_in[5];
  const float* h_b2    = (const float*)d_in[6];
  const float* cls_tok = (const float*)d_in[7];
  const float* pos_emb = (const float*)d_in[8];
  const float* ln1_s   = (const float*)d_in[9];
  const float* ln1_b   = (const float*)d_in[10];
  const float* qkv_w   = (const float*)d_in[11];
  const float* qkv_b   = (const float*)d_in[12];
  const float* proj_w  = (const float*)d_in[13];
  const float* proj_b  = (const float*)d_in[14];
  const float* ln2_s   = (const float*)d_in[15];
  const float* ln2_b   = (const float*)d_in[16];
  const float* mlp_w1  = (const float*)d_in[17];
  const float* mlp_b1  = (const float*)d_in[18];
  const float* mlp_w2  = (const float*)d_in[19];
  const float* mlp_b2  = (const float*)d_in[20];
  const float* fin_s   = (const float*)d_in[21];
  const float* fin_b   = (const float*)d_in[22];
  const float* cls_w   = (const float*)d_in[23];
  const float* cls_b   = (const float*)d_in[24];

  size_t off = 0;
  char* wsb = (char*)d_ws;
  auto take = [&](size_t bytes) -> void* {
    void* p = wsb + off;
    off += (bytes + 255) & ~(size_t)255;
    return p;
  };
  uint16_t* h1w  = (uint16_t*)take((size_t)512 * 192 * 2);
  uint16_t* h2w  = (uint16_t*)take((size_t)512 * 512 * 2);
  uint16_t* wq   = (uint16_t*)take((size_t)1536 * 512 * 2);   // per-layer qkv W^T
  uint16_t* wp   = (uint16_t*)take((size_t)512 * 512 * 2);    // per-layer proj W^T
  uint16_t* w1   = (uint16_t*)take((size_t)2048 * 512 * 2);   // per-layer mlp1 W^T
  uint16_t* w2   = (uint16_t*)take((size_t)512 * 2048 * 2);   // per-layer mlp2 W^T
  float*    h    = (float*)take((size_t)NTOK * 512 * 4);      // f32 residual stream
  uint16_t* nbuf = (uint16_t*)take((size_t)NTOK * 512 * 2);   // LN out / attn out
  uint16_t* big  = (uint16_t*)take((size_t)NTOK * 1024 * 2);  // qkv-half  OR  mlp mid-half
  size_t needed = off;
  if (needed > ws_size) return;  // diagnostic: fail with untouched output instead of faulting

  uint16_t* pbuf = big;                                 // patches (32768 x 192)
  uint16_t* hid1 = nbuf;                                // fc1 out (32768 x 512)

  dim3 blk(256);
  // patch-MLP weights -> bf16 transposed (once)
  transpose_cast<<<dim3(8, 3), blk, 0, stream>>>(h_w1, h1w, 192, 512);
  transpose_cast<<<dim3(8, 8), blk, 0, stream>>>(h_w2, h2w, 512, 512);

  // conv + patchify
  conv_patch<<<dim3(NB * 12), blk, 0, stream>>>(x, conv_w, conv_b, pbuf);
  // patch MLP
  gemm_bf16<1><<<dim3(4, 256), blk, 0, stream>>>(pbuf, h1w, h_b1, hid1, nullptr, nullptr,
                                                 NPAT, 512, 192, 192, 192, 512);
  gemm_bf16<4><<<dim3(4, 256), blk, 0, stream>>>(hid1, h2w, h_b2, nullptr, h, pos_emb,
                                                 NPAT, 512, 512, 512, 512, 512);
  fill_cls<<<dim3(NB), dim3(512), 0, stream>>>(cls_tok, pos_emb, h);

  for (int l = 0; l < 12; l++) {
    // per-layer weights -> bf16 W^T
    transpose_cast<<<dim3(24, 8), blk, 0, stream>>>(qkv_w + (size_t)l * 512 * 1536, wq, 512, 1536);
    transpose_cast<<<dim3(8, 8), blk, 0, stream>>>(proj_w + (size_t)l * 512 * 512, wp, 512, 512);
    transpose_cast<<<dim3(32, 8), blk, 0, stream>>>(mlp_w1 + (size_t)l * 512 * 2048, w1, 512, 2048);
    transpose_cast<<<dim3(8, 32), blk, 0, stream>>>(mlp_w2 + (size_t)l * 2048 * 512, w2, 2048, 512);

    ln_kernel<<<dim3(NTOK), blk, 0, stream>>>(h, ln1_s + l * 512, ln1_b + l * 512, nbuf);
    // qkv + attention in two batch halves (big holds 17408 x 1536)
    for (int half = 0; half < 2; half++) {
      int tok0 = half * HALFTOK;
      gemm_bf16<0><<<dim3(12, 136), blk, 0, stream>>>(nbuf + (size_t)tok0 * 512, wq, qkv_b + l * 1536,
                                                      big, nullptr, nullptr,
                                                      HALFTOK, 1536, 512, 512, 512, 1536);
      attn_kernel<<<dim3(1024 * 16), dim3(64), 0, stream>>>(big, nbuf, tok0);
    }
    gemm_bf16<3><<<dim3(4, 272), blk, 0, stream>>>(nbuf, wp, proj_b + l * 512,
                                                   nullptr, h, nullptr,
                                                   NTOK, 512, 512, 512, 512, 512);
    ln_kernel<<<dim3(NTOK), blk, 0, stream>>>(h, ln2_s + l * 512, ln2_b + l * 512, nbuf);
    // MLP in two DFF halves (big holds 34816 x 1024)
    for (int c = 0; c < 2; c++) {
      gemm_bf16<2><<<dim3(8, 272), blk, 0, stream>>>(nbuf, w1 + (size_t)c * 1024 * 512,
                                                     mlp_b1 + l * 2048 + c * 1024,
                                                     big, nullptr, nullptr,
                                                     NTOK, 1024, 512, 512, 512, 1024);
      gemm_bf16<3><<<dim3(4, 272), blk, 0, stream>>>(big, w2 + c * 1024,
                                                     c == 0 ? mlp_b2 + l * 512 : nullptr,
                                                     nullptr, h, nullptr,
                                                     NTOK, 512, 1024, 1024, 2048, 512);
    }
  }
  final_head<<<dim3(NB), dim3(64), 0, stream>>>(h, fin_s, fin_b, cls_w, cls_b, (float*)d_out);
}

// Round 3
// 9845.690 us; speedup vs baseline: 1.1083x; 1.1083x over previous
//
#include <hip/hip_runtime.h>
#include <stdint.h>

// ---------------- constants ----------------
#define NB   2048          // batch
#define SEQ  17
#define DIM  512
#define NTOK (NB * SEQ)    // 34816 rows (= 272*128)
#define NPAT (NB * 16)     // 32768 rows (= 256*128)
#define HALFTOK (NTOK / 2) // 17408 (= 136*128)

typedef __bf16 v8bf __attribute__((ext_vector_type(8)));
typedef float  f32x4 __attribute__((ext_vector_type(4)));

typedef const __attribute__((address_space(1))) void GVoid;
typedef __attribute__((address_space(3))) void LVoid;

__device__ __forceinline__ uint16_t f2bf(float f) {
  uint32_t u = __float_as_uint(f);
  uint32_t r = u + 0x7FFFu + ((u >> 16) & 1u);
  return (uint16_t)(r >> 16);
}
__device__ __forceinline__ float bf2f(uint16_t h) {
  return __uint_as_float(((uint32_t)h) << 16);
}
__device__ __forceinline__ void load16_lds(const void* g, void* l) {
  __builtin_amdgcn_global_load_lds((GVoid*)g, (LVoid*)l, 16, 0, 0);
}

// ---------------- weight transpose+cast: (K,N) f32 -> (N,K) bf16 ----------------
__global__ __launch_bounds__(256) void transpose_cast(
    const float* __restrict__ in, uint16_t* __restrict__ out, int K, int N) {
  __shared__ uint16_t t[64][65];
  int k0 = blockIdx.y * 64, n0 = blockIdx.x * 64;
  int tid = threadIdx.x;
  int c = tid & 63, r0 = tid >> 6;
#pragma unroll
  for (int i = 0; i < 16; i++) {
    int r = i * 4 + r0;
    t[c][r] = f2bf(in[(size_t)(k0 + r) * N + n0 + c]);
  }
  __syncthreads();
#pragma unroll
  for (int i = 0; i < 16; i++) {
    int rn = i * 4 + r0;
    out[(size_t)(n0 + rn) * K + k0 + c] = t[rn][c];
  }
}

// ---------------- xpad: zero-padded image, bf16 [NB][3][48][48] ----------------
__global__ __launch_bounds__(256) void xpad_fill(
    const float* __restrict__ x, uint16_t* __restrict__ xp) {
  int idx = blockIdx.x * 256 + threadIdx.x;      // NB*3*48*6 = 1,769,472 chunks of 8
  int c8 = idx % 6;
  int r = (idx / 6) % 48;
  int i = (idx / 288) % 3;
  int b = idx / 864;
  int col0 = c8 * 8;
  uint16_t v[8];
  const float* src = x + ((size_t)(b * 3 + i) * 32 + (r - 7)) * 32;
#pragma unroll
  for (int e = 0; e < 8; e++) {
    int col = col0 + e;
    float val = (r >= 7 && r < 39 && col >= 7 && col < 39) ? src[col - 7] : 0.f;
    v[e] = f2bf(val);
  }
  *(uint4*)&xp[(((size_t)b * 3 + i) * 48 + r) * 48 + col0] = *(const uint4*)v;
}

// ---------------- G: gathered conv kernel matrix, bf16 [1792][192] ----------------
// G[k=(i,dy,dx)][j=(o,ry,rx)] = w[o,i,dy-ry,dx-rx] (0 if out of range)
__global__ __launch_bounds__(256) void build_G(
    const float* __restrict__ w, uint16_t* __restrict__ G) {
  int idx = blockIdx.x * 256 + threadIdx.x;      // 1792*192 = 344064
  if (idx >= 1792 * 192) return;
  int j = idx % 192, k = idx / 192;
  int o = j >> 6, ry = (j >> 3) & 7, rx = j & 7;
  int i = k / 576, rem = k - i * 576;
  int dy = rem / 24, dx = rem % 24;
  float val = 0.f;
  if (i < 3) {
    int ky = dy - ry, kx = dx - rx;
    if (ky >= 0 && ky < 16 && kx >= 0 && kx < 16)
      val = w[o * 768 + i * 256 + ky * 16 + kx];
  }
  G[idx] = f2bf(val);
}

// ---------------- effective bias: h_b1[d] + sum_o cb[o]*sum_{ry,rx} W1[(o,ry,rx),d] ----------
__global__ __launch_bounds__(256) void bias_eff_kernel(
    const float* __restrict__ h_b1, const float* __restrict__ cb,
    const uint16_t* __restrict__ h1w, float* __restrict__ be) {
  int d = blockIdx.x * 256 + threadIdx.x;        // 512
  if (d >= 512) return;
  float s = h_b1[d];
#pragma unroll
  for (int o = 0; o < 3; o++) {
    float so = 0.f;
    for (int j = 0; j < 64; j++) so += bf2f(h1w[(size_t)d * 192 + o * 64 + j]);
    s += cb[o] * so;
  }
  be[d] = s;
}

// ---------------- GEMM: C(MxN) = A(M x K) * W^T(N x K, ldw) + bias ----------
// EPI: 0=bias->bf16  1=bias+leaky->bf16  2=bias+gelu->bf16  3=in-place f32 accumulate
//      4=patch scatter + pos_emb -> f32
// ASRC: 0 = row-major A (stride lda); 1 = xpad patch windows (A = xpad base, K=1728)
template <int EPI, int ASRC>
__global__ __launch_bounds__(256) void gemm_bf16(
    const uint16_t* __restrict__ A, const uint16_t* __restrict__ W,
    const float* __restrict__ bias, uint16_t* __restrict__ outb,
    float* __restrict__ outf, const float* __restrict__ pos,
    int M, int N, int K, int lda, int ldw, int ldo) {
  __shared__ uint16_t As[128 * 64];
  __shared__ uint16_t Bs[128 * 64];
  const int tid = threadIdx.x;
  const int w = tid >> 6, l = tid & 63;
  const int lr = l & 15, lk = l >> 4;
  const int wr = w >> 1, wc = w & 1;

  // XCD-chunked block swizzle (grids here always have nwg % 8 == 0)
  int flat = blockIdx.y * gridDim.x + blockIdx.x;
  int nwg = gridDim.x * gridDim.y;
  int chunk = nwg >> 3;
  int f2 = (flat & 7) * chunk + (flat >> 3);
  const int m0 = (f2 / gridDim.x) * 128, n0 = (f2 % gridDim.x) * 128;

  f32x4 acc[4][4];
#pragma unroll
  for (int i = 0; i < 4; i++)
#pragma unroll
    for (int j = 0; j < 4; j++) acc[i][j] = (f32x4){0.f, 0.f, 0.f, 0.f};

  const int gr = l >> 3;        // row within 8-row segment
  const int gc = (l & 7) * 8;   // element col

  size_t abase[4];
  if (ASRC == 1) {
#pragma unroll
    for (int s = 0; s < 4; s++) {
      int r = m0 + (w * 4 + s) * 8 + gr;
      int b = r >> 4, patch = r & 15;
      int py = patch >> 2, px = patch & 3;
      abase[s] = (size_t)b * 6912 + py * 8 * 48 + px * 8;
    }
  }

  const int nkt = K >> 6;
  for (int kt = 0; kt < nkt; kt++) {
    const uint16_t* Bb = W + (size_t)n0 * ldw + kt * 64;
    if (ASRC == 0) {
      const uint16_t* Ab = A + (size_t)m0 * lda + kt * 64;
#pragma unroll
      for (int i = 0; i < 4; i++) {
        int seg = w * 4 + i;
        int r = seg * 8 + gr;
        load16_lds(Ab + (size_t)r * lda + gc, &As[seg * 512]);
        load16_lds(Bb + (size_t)r * ldw + gc, &Bs[seg * 512]);
      }
    } else {
      int c = kt * 8 + (l & 7);
      int ii = c / 72, rem = c - ii * 72;
      int dy = rem / 3, dx0 = (rem - dy * 3) * 8;
      size_t koff = (size_t)ii * 2304 + dy * 48 + dx0;
#pragma unroll
      for (int i = 0; i < 4; i++) {
        int seg = w * 4 + i;
        int r = seg * 8 + gr;
        load16_lds(A + abase[i] + koff, &As[seg * 512]);
        load16_lds(Bb + (size_t)r * ldw + gc, &Bs[seg * 512]);
      }
    }
    __syncthreads();
#pragma unroll
    for (int kk = 0; kk < 64; kk += 32) {
      v8bf a[4], b[4];
#pragma unroll
      for (int mi = 0; mi < 4; mi++)
        a[mi] = *(const v8bf*)&As[(wr * 64 + mi * 16 + lr) * 64 + kk + lk * 8];
#pragma unroll
      for (int ni = 0; ni < 4; ni++)
        b[ni] = *(const v8bf*)&Bs[(wc * 64 + ni * 16 + lr) * 64 + kk + lk * 8];
#pragma unroll
      for (int mi = 0; mi < 4; mi++)
#pragma unroll
        for (int ni = 0; ni < 4; ni++)
          acc[mi][ni] = __builtin_amdgcn_mfma_f32_16x16x32_bf16(a[mi], b[ni], acc[mi][ni], 0, 0, 0);
    }
    __syncthreads();
  }

#pragma unroll
  for (int mi = 0; mi < 4; mi++) {
#pragma unroll
    for (int ni = 0; ni < 4; ni++) {
      int col = n0 + wc * 64 + ni * 16 + lr;
      float bv = bias ? bias[col] : 0.f;
#pragma unroll
      for (int q = 0; q < 4; q++) {
        int row = m0 + wr * 64 + mi * 16 + lk * 4 + q;
        float v = acc[mi][ni][q] + bv;
        if (EPI == 0) {
          outb[(size_t)row * ldo + col] = f2bf(v);
        } else if (EPI == 1) {
          v = v > 0.f ? v : 0.1f * v;
          outb[(size_t)row * ldo + col] = f2bf(v);
        } else if (EPI == 2) {
          v = 0.5f * v * (1.f + erff(v * 0.70710678118654752f));
          outb[(size_t)row * ldo + col] = f2bf(v);
        } else if (EPI == 3) {
          outf[(size_t)row * ldo + col] += v;
        } else {
          int bb = row >> 4, ss = row & 15;
          outf[((size_t)bb * 17 + ss) * 512 + col] = v + pos[ss * 512 + col];
        }
      }
    }
  }
}

// ---------------- LayerNorm rows of h (f32) -> bf16 ----------------
__global__ __launch_bounds__(256) void ln_kernel(
    const float* __restrict__ h, const float* __restrict__ s,
    const float* __restrict__ b, uint16_t* __restrict__ out) {
  int row = blockIdx.x;
  const float* x = h + (size_t)row * 512;
  int tid = threadIdx.x;
  float v0 = x[tid], v1 = x[tid + 256];
  float sum = v0 + v1, sq = v0 * v0 + v1 * v1;
#pragma unroll
  for (int off = 1; off < 64; off <<= 1) {
    sum += __shfl_xor(sum, off);
    sq += __shfl_xor(sq, off);
  }
  __shared__ float sm[4], sv[4];
  int wid = tid >> 6;
  if ((tid & 63) == 0) { sm[wid] = sum; sv[wid] = sq; }
  __syncthreads();
  sum = sm[0] + sm[1] + sm[2] + sm[3];
  sq = sv[0] + sv[1] + sv[2] + sv[3];
  float mean = sum * (1.f / 512.f);
  float var = sq * (1.f / 512.f) - mean * mean;
  float rs = rsqrtf(var + 1e-5f);
  out[(size_t)row * 512 + tid] = f2bf((v0 - mean) * rs * s[tid] + b[tid]);
  out[(size_t)row * 512 + tid + 256] = f2bf((v1 - mean) * rs * s[tid + 256] + b[tid + 256]);
}

// ---------------- attention per (b,h): 64 threads; qkv is a half-batch buffer ----------
__global__ __launch_bounds__(64) void attn_kernel(
    const uint16_t* __restrict__ qkv, uint16_t* __restrict__ o, int tok0) {
  int bh = blockIdx.x;
  int b = bh >> 4, h = bh & 15;
  __shared__ float Q[17][32], Kk[17][32], V[17][32], P[17][18];
  int tid = threadIdx.x;
  const uint16_t* base = qkv + (size_t)b * SEQ * 1536 + h * 32;
  for (int idx = tid; idx < 544; idx += 64) {
    int s = idx >> 5, d = idx & 31;
    const uint16_t* rp = base + (size_t)s * 1536 + d;
    Q[s][d] = bf2f(rp[0]);
    Kk[s][d] = bf2f(rp[512]);
    V[s][d] = bf2f(rp[1024]);
  }
  __syncthreads();
  for (int idx = tid; idx < 289; idx += 64) {
    int i = idx / 17, j = idx % 17;
    float acc = 0.f;
#pragma unroll
    for (int d = 0; d < 32; d++) acc += Q[i][d] * Kk[j][d];
    P[i][j] = acc * 0.17677669529663687f;
  }
  __syncthreads();
  if (tid < 17) {
    float m = -1e30f;
    for (int j = 0; j < 17; j++) m = fmaxf(m, P[tid][j]);
    float sum = 0.f;
    for (int j = 0; j < 17; j++) { float e = __expf(P[tid][j] - m); P[tid][j] = e; sum += e; }
    float inv = 1.f / sum;
    for (int j = 0; j < 17; j++) P[tid][j] *= inv;
  }
  __syncthreads();
  uint16_t* ob = o + ((size_t)tok0 + (size_t)b * SEQ) * 512 + h * 32;
  for (int idx = tid; idx < 544; idx += 64) {
    int s = idx >> 5, d = idx & 31;
    float acc = 0.f;
#pragma unroll
    for (int t = 0; t < 17; t++) acc += P[s][t] * V[t][d];
    ob[(size_t)s * 512 + d] = f2bf(acc);
  }
}

// ---------------- cls token row fill ----------------
__global__ void fill_cls(const float* __restrict__ cls_tok,
                         const float* __restrict__ pos, float* __restrict__ h) {
  int b = blockIdx.x, d = threadIdx.x;
  h[((size_t)b * SEQ + 16) * 512 + d] = cls_tok[d] + pos[16 * 512 + d];
}

// ---------------- final LN (row 0) + classifier ----------------
__global__ __launch_bounds__(64) void final_head(
    const float* __restrict__ h, const float* __restrict__ fs,
    const float* __restrict__ fb, const float* __restrict__ cw,
    const float* __restrict__ cb, float* __restrict__ out) {
  int b = blockIdx.x;
  const float* x = h + (size_t)b * SEQ * 512;
  int l = threadIdx.x;
  float v[8];
  float sum = 0.f, sq = 0.f;
#pragma unroll
  for (int i = 0; i < 8; i++) { v[i] = x[l * 8 + i]; sum += v[i]; sq += v[i] * v[i]; }
#pragma unroll
  for (int off = 1; off < 64; off <<= 1) { sum += __shfl_xor(sum, off); sq += __shfl_xor(sq, off); }
  float mean = sum * (1.f / 512.f);
  float var = sq * (1.f / 512.f) - mean * mean;
  float rs = rsqrtf(var + 1e-5f);
  __shared__ float n[512];
#pragma unroll
  for (int i = 0; i < 8; i++) n[l * 8 + i] = (v[i] - mean) * rs * fs[l * 8 + i] + fb[l * 8 + i];
  __syncthreads();
  if (l < 10) {
    float acc = cb[l];
    for (int d = 0; d < 512; d++) acc += n[d] * cw[d * 10 + l];
    out[(size_t)b * 10 + l] = acc;
  }
}

// ---------------- launch ----------------
extern "C" void kernel_launch(void* const* d_in, const int* in_sizes, int n_in,
                              void* d_out, int out_size, void* d_ws, size_t ws_size,
                              hipStream_t stream) {
  const float* x       = (const float*)d_in[0];
  const float* conv_w  = (const float*)d_in[1];
  const float* conv_b  = (const float*)d_in[2];
  const float* h_w1    = (const float*)d_in[3];
  const float* h_b1    = (const float*)d_in[4];
  const float* h_w2    = (const float*)d_in[5];
  const float* h_b2    = (const float*)d_in[6];
  const float* cls_tok = (const float*)d_in[7];
  const float* pos_emb = (const float*)d_in[8];
  const float* ln1_s   = (const float*)d_in[9];
  const float* ln1_b   = (const float*)d_in[10];
  const float* qkv_w   = (const float*)d_in[11];
  const float* qkv_b   = (const float*)d_in[12];
  const float* proj_w  = (const float*)d_in[13];
  const float* proj_b  = (const float*)d_in[14];
  const float* ln2_s   = (const float*)d_in[15];
  const float* ln2_b   = (const float*)d_in[16];
  const float* mlp_w1  = (const float*)d_in[17];
  const float* mlp_b1  = (const float*)d_in[18];
  const float* mlp_w2  = (const float*)d_in[19];
  const float* mlp_b2  = (const float*)d_in[20];
  const float* fin_s   = (const float*)d_in[21];
  const float* fin_b   = (const float*)d_in[22];
  const float* cls_w   = (const float*)d_in[23];
  const float* cls_b   = (const float*)d_in[24];

  size_t off = 0;
  char* wsb = (char*)d_ws;
  auto take = [&](size_t bytes) -> void* {
    void* p = wsb + off;
    off += (bytes + 255) & ~(size_t)255;
    return p;
  };
  uint16_t* h1w  = (uint16_t*)take((size_t)512 * 192 * 2);
  uint16_t* h2w  = (uint16_t*)take((size_t)512 * 512 * 2);
  uint16_t* wq   = (uint16_t*)take((size_t)1536 * 512 * 2);
  uint16_t* wp   = (uint16_t*)take((size_t)512 * 512 * 2);
  uint16_t* w1   = (uint16_t*)take((size_t)2048 * 512 * 2);
  uint16_t* w2   = (uint16_t*)take((size_t)512 * 2048 * 2);
  float*    h    = (float*)take((size_t)NTOK * 512 * 4);
  uint16_t* nbuf = (uint16_t*)take((size_t)NTOK * 512 * 2);
  uint16_t* big  = (uint16_t*)take((size_t)NTOK * 1024 * 2);
  if (off > ws_size) return;

  // conv-prologue scratch aliased into `big` (free until first qkv GEMM)
  uint16_t* xpad = big;                                        // 28,311,552 B
  uint16_t* G    = (uint16_t*)((char*)big + 28311552);         //    688,128 B
  uint16_t* weff = (uint16_t*)((char*)big + 28311552 + 688128);// 1,835,008 B
  float*    beff = (float*)((char*)big + 28311552 + 688128 + 1835008);
  uint16_t* hid1 = nbuf;

  dim3 blk(256);
  transpose_cast<<<dim3(8, 3), blk, 0, stream>>>(h_w1, h1w, 192, 512);
  transpose_cast<<<dim3(8, 8), blk, 0, stream>>>(h_w2, h2w, 512, 512);

  // folded conv + patch-MLP-1
  xpad_fill<<<dim3(NB * 3 * 48 * 6 / 256), blk, 0, stream>>>(x, xpad);
  build_G<<<dim3((1792 * 192 + 255) / 256), blk, 0, stream>>>(conv_w, G);
  bias_eff_kernel<<<dim3(2), blk, 0, stream>>>(h_b1, conv_b, h1w, beff);
  // weff[d][k] = sum_j h1w[d][j] * G[k][j]  (M=512, N=1792, K=192)
  gemm_bf16<0, 0><<<dim3(14, 4), blk, 0, stream>>>(h1w, G, nullptr, weff, nullptr, nullptr,
                                                   512, 1792, 192, 192, 192, 1792);
  // hid1 = leaky(xpad_windows @ weff^T + beff)  (M=32768, N=512, K=1728)
  gemm_bf16<1, 1><<<dim3(4, 256), blk, 0, stream>>>(xpad, weff, beff, hid1, nullptr, nullptr,
                                                    NPAT, 512, 1728, 0, 1792, 512);
  // h = hid1 @ h_w2 + h_b2, scattered to (b,s) layout + pos_emb
  gemm_bf16<4, 0><<<dim3(4, 256), blk, 0, stream>>>(hid1, h2w, h_b2, nullptr, h, pos_emb,
                                                    NPAT, 512, 512, 512, 512, 512);
  fill_cls<<<dim3(NB), dim3(512), 0, stream>>>(cls_tok, pos_emb, h);

  for (int l = 0; l < 12; l++) {
    transpose_cast<<<dim3(24, 8), blk, 0, stream>>>(qkv_w + (size_t)l * 512 * 1536, wq, 512, 1536);
    transpose_cast<<<dim3(8, 8), blk, 0, stream>>>(proj_w + (size_t)l * 512 * 512, wp, 512, 512);
    transpose_cast<<<dim3(32, 8), blk, 0, stream>>>(mlp_w1 + (size_t)l * 512 * 2048, w1, 512, 2048);
    transpose_cast<<<dim3(8, 32), blk, 0, stream>>>(mlp_w2 + (size_t)l * 2048 * 512, w2, 2048, 512);

    ln_kernel<<<dim3(NTOK), blk, 0, stream>>>(h, ln1_s + l * 512, ln1_b + l * 512, nbuf);
    for (int half = 0; half < 2; half++) {
      int tok0 = half * HALFTOK;
      gemm_bf16<0, 0><<<dim3(12, 136), blk, 0, stream>>>(nbuf + (size_t)tok0 * 512, wq, qkv_b + l * 1536,
                                                         big, nullptr, nullptr,
                                                         HALFTOK, 1536, 512, 512, 512, 1536);
      attn_kernel<<<dim3(1024 * 16), dim3(64), 0, stream>>>(big, nbuf, tok0);
    }
    gemm_bf16<3, 0><<<dim3(4, 272), blk, 0, stream>>>(nbuf, wp, proj_b + l * 512,
                                                      nullptr, h, nullptr,
                                                      NTOK, 512, 512, 512, 512, 512);
    ln_kernel<<<dim3(NTOK), blk, 0, stream>>>(h, ln2_s + l * 512, ln2_b + l * 512, nbuf);
    for (int c = 0; c < 2; c++) {
      gemm_bf16<2, 0><<<dim3(8, 272), blk, 0, stream>>>(nbuf, w1 + (size_t)c * 1024 * 512,
                                                        mlp_b1 + l * 2048 + c * 1024,
                                                        big, nullptr, nullptr,
                                                        NTOK, 1024, 512, 512, 512, 1024);
      gemm_bf16<3, 0><<<dim3(4, 272), blk, 0, stream>>>(big, w2 + c * 1024,
                                                        c == 0 ? mlp_b2 + l * 512 : nullptr,
                                                        nullptr, h, nullptr,
                                                        NTOK, 512, 1024, 1024, 2048, 512);
    }
  }
  final_head<<<dim3(NB), dim3(64), 0, stream>>>(h, fin_s, fin_b, cls_w, cls_b, (float*)d_out);
}